// Round 6
// baseline (23.657 us; speedup 1.0000x reference)
//
#include <hip/hip_runtime.h>
#include <math.h>

#define BATCH 64
#define TLEN 8000
#define NCHUNK 4
#define TPC (TLEN / NCHUNK)     // 2000 frames per chunk
#define NPART 21                // 16 (M) + 4 (V) + 1 (mask sum)
#define NBLOCKS (NCHUNK * BATCH)              // 256 blocks = 1 per CU
#define TICKET_OFF (NCHUNK * NPART * BATCH)   // floats before the ticket

// fast, stable log-sigmoid: min(x,0) - log(1 + exp(-|x|))
__device__ __forceinline__ float log_sigmoid_f(float x) {
    float e = __expf(-fabsf(x));
    return fminf(x, 0.0f) - __logf(1.0f + e);
}

__global__ __launch_bounds__(256) void pit_onepass(
    const float* __restrict__ logits, const float* __restrict__ targets,
    const float* __restrict__ mask, float* __restrict__ ws,
    unsigned int* __restrict__ ticket, float* __restrict__ out)
{
    const int chunk = blockIdx.x;   // 0..NCHUNK-1
    const int b     = blockIdx.y;   // 0..BATCH-1
    const int tid   = threadIdx.x;
    const int t0    = chunk * TPC;

    float M[4][4] = {{0.f}};
    float V[4] = {0.f};
    float msum = 0.f;

    const float4* lg4 = (const float4*)(logits  + (size_t)b * TLEN * 4);
    const float4* tg4 = (const float4*)(targets + (size_t)b * TLEN * 4);
    const float*  mk  = mask + (size_t)b * TLEN;

    for (int t = t0 + tid; t < t0 + TPC; t += 256) {
        float4 xv = lg4[t];
        float4 tv = tg4[t];
        float  m  = mk[t];
        float xs[4] = {xv.x, xv.y, xv.z, xv.w};
        float ts[4] = {tv.x, tv.y, tv.z, tv.w};
        msum += m;
        #pragma unroll
        for (int i = 0; i < 4; ++i) {
            float A  = log_sigmoid_f(xs[i]);
            float Bn = A - xs[i];            // log_sigmoid(-x)
            float C  = fmaf(0.5f, A, xs[i]); // POS_W*A - Bn with POS_W=1.5
            V[i] = fmaf(m, Bn, V[i]);
            float mc = m * C;
            #pragma unroll
            for (int j = 0; j < 4; ++j)
                M[i][j] = fmaf(mc, ts[j], M[i][j]);
        }
    }

    // ---- 3-stage deterministic LDS reduction (2 syncthreads) ----
    __shared__ float red[256 * NPART];          // 21504 B
    __shared__ float red2[8 * NPART];
    #pragma unroll
    for (int i = 0; i < 4; ++i)
        #pragma unroll
        for (int j = 0; j < 4; ++j)
            red[tid * NPART + i * 4 + j] = M[i][j];
    #pragma unroll
    for (int i = 0; i < 4; ++i) red[tid * NPART + 16 + i] = V[i];
    red[tid * NPART + 20] = msum;
    __syncthreads();

    {   // 8 segments x 21 parts = 168 workers, each sums 32 rows
        const int seg = tid >> 5;
        const int k   = tid & 31;
        if (k < NPART) {
            float acc = 0.f;
            #pragma unroll
            for (int i = 0; i < 32; ++i)
                acc += red[(seg * 32 + i) * NPART + k];
            red2[seg * NPART + k] = acc;
        }
    }
    __syncthreads();

    if (tid < NPART) {
        float acc = 0.f;
        #pragma unroll
        for (int s = 0; s < 8; ++s)
            acc += red2[s * NPART + tid];
        // device-coherent write-through store (sc0/sc1) — no L2 flush
        __hip_atomic_store(&ws[(chunk * NPART + tid) * BATCH + b], acc,
                           __ATOMIC_RELAXED, __HIP_MEMORY_SCOPE_AGENT);
    }

    // __syncthreads drains vmcnt(0) before s_barrier -> the 21 coherent
    // stores are globally visible before tid 0 increments the ticket.
    __syncthreads();

    __shared__ bool amLast;
    if (tid == 0)
        amLast = (__hip_atomic_fetch_add(ticket, 1u, __ATOMIC_RELAXED,
                                         __HIP_MEMORY_SCOPE_AGENT)
                  == NBLOCKS - 1u);
    __syncthreads();
    if (!amLast) return;

    // ---- final phase, last-arriving block, 256 threads ----
    // thread = (chunk c = tid>>6, batch bb = tid&63): load its 21 partials
    {
        const int c  = tid >> 6;
        const int bb = tid & 63;
        #pragma unroll
        for (int k = 0; k < NPART; ++k) {
            float v = __hip_atomic_load(&ws[(c * NPART + k) * BATCH + bb],
                                        __ATOMIC_RELAXED,
                                        __HIP_MEMORY_SCOPE_AGENT);
            red[(c * 64 + bb) * NPART + k] = v;   // reuse LDS
        }
    }
    __syncthreads();

    if (tid < 64) {
        const int bb = tid;
        float p[NPART];
        #pragma unroll
        for (int k = 0; k < NPART; ++k) {
            float acc = 0.f;
            #pragma unroll
            for (int c = 0; c < NCHUNK; ++c)
                acc += red[(c * 64 + bb) * NPART + k];
            p[k] = acc;
        }

        const float denom = fmaxf(p[20], 1.0f);
        float cost[4][4];
        #pragma unroll
        for (int i = 0; i < 4; ++i)
            #pragma unroll
            for (int j = 0; j < 4; ++j)
                cost[i][j] = -(p[i * 4 + j] + p[16 + i]) / denom;

        constexpr int PERMS[24][4] = {
            {0,1,2,3},{0,1,3,2},{0,2,1,3},{0,2,3,1},{0,3,1,2},{0,3,2,1},
            {1,0,2,3},{1,0,3,2},{1,2,0,3},{1,2,3,0},{1,3,0,2},{1,3,2,0},
            {2,0,1,3},{2,0,3,1},{2,1,0,3},{2,1,3,0},{2,3,0,1},{2,3,1,0},
            {3,0,1,2},{3,0,2,1},{3,1,0,2},{3,1,2,0},{3,2,0,1},{3,2,1,0}};
        float best = 3.4e38f;
        #pragma unroll
        for (int pi = 0; pi < 24; ++pi) {
            float s4 = cost[0][PERMS[pi][0]] + cost[1][PERMS[pi][1]]
                     + cost[2][PERMS[pi][2]] + cost[3][PERMS[pi][3]];
            best = fminf(best, s4);
        }
        float loss = best * 0.25f;

        #pragma unroll
        for (int off = 32; off > 0; off >>= 1)
            loss += __shfl_down(loss, off);
        if (bb == 0) out[0] = loss * (1.0f / BATCH);
    }
}

extern "C" void kernel_launch(void* const* d_in, const int* in_sizes, int n_in,
                              void* d_out, int out_size, void* d_ws, size_t ws_size,
                              hipStream_t stream) {
    const float* logits  = (const float*)d_in[0];
    const float* targets = (const float*)d_in[1];
    const float* mask    = (const float*)d_in[2];
    float* out = (float*)d_out;
    float* ws  = (float*)d_ws;
    unsigned int* ticket = (unsigned int*)(ws + TICKET_OFF);

    // zero the ticket each call (handles 0xAA poison + resets between replays)
    hipMemsetAsync(ticket, 0, sizeof(unsigned int), stream);

    pit_onepass<<<dim3(NCHUNK, BATCH), 256, 0, stream>>>(
        logits, targets, mask, ws, ticket, out);
}

// Round 7
// 21.251 us; speedup vs baseline: 1.1132x; 1.1132x over previous
//
#include <hip/hip_runtime.h>
#include <math.h>

#define BATCH 64
#define TLEN 8000
#define NTHREADS 1024
#define NWAVES (NTHREADS / 64)
#define NPART 21                 // 16 (M) + 4 (V) + 1 (mask sum)
#define TICKET_OFF 64            // floats before the ticket in ws

// fast, stable log-sigmoid: min(x,0) - log(1 + exp(-|x|))
__device__ __forceinline__ float log_sigmoid_f(float x) {
    float e = __expf(-fabsf(x));
    return fminf(x, 0.0f) - __logf(1.0f + e);
}

__global__ __launch_bounds__(NTHREADS) void pit_batch(
    const float* __restrict__ logits, const float* __restrict__ targets,
    const float* __restrict__ mask, float* __restrict__ ws,
    unsigned int* __restrict__ ticket, float* __restrict__ out)
{
    const int b    = blockIdx.x;     // one block per batch element
    const int tid  = threadIdx.x;
    const int wid  = tid >> 6;
    const int lane = tid & 63;

    __shared__ float wred[NWAVES][NPART];
    __shared__ float pshare[NPART];
    __shared__ float costl[16];
    __shared__ bool  amLast;

    float acc[NPART];
    #pragma unroll
    for (int k = 0; k < NPART; ++k) acc[k] = 0.f;

    const float4* lg4 = (const float4*)(logits  + (size_t)b * TLEN * 4);
    const float4* tg4 = (const float4*)(targets + (size_t)b * TLEN * 4);
    const float*  mk  = mask + (size_t)b * TLEN;

    for (int t = tid; t < TLEN; t += NTHREADS) {
        float4 xv = lg4[t];
        float4 tv = tg4[t];
        float  m  = mk[t];
        float xs[4] = {xv.x, xv.y, xv.z, xv.w};
        float ts[4] = {tv.x, tv.y, tv.z, tv.w};
        acc[20] += m;
        #pragma unroll
        for (int i = 0; i < 4; ++i) {
            float A  = log_sigmoid_f(xs[i]);
            float Bn = A - xs[i];            // log_sigmoid(-x)
            float C  = fmaf(0.5f, A, xs[i]); // POS_W*A - Bn, POS_W = 1.5
            acc[16 + i] = fmaf(m, Bn, acc[16 + i]);
            float mc = m * C;
            #pragma unroll
            for (int j = 0; j < 4; ++j)
                acc[i * 4 + j] = fmaf(mc, ts[j], acc[i * 4 + j]);
        }
    }

    // ---- 64-lane butterfly (fixed order, deterministic) ----
    #pragma unroll
    for (int k = 0; k < NPART; ++k) {
        #pragma unroll
        for (int off = 32; off > 0; off >>= 1)
            acc[k] += __shfl_xor(acc[k], off);
    }
    if (lane == 0) {
        #pragma unroll
        for (int k = 0; k < NPART; ++k) wred[wid][k] = acc[k];
    }
    __syncthreads();

    // ---- per-batch finish on wave 0 ----
    if (tid < NPART) {
        float p = 0.f;
        #pragma unroll
        for (int w = 0; w < NWAVES; ++w) p += wred[w][tid];
        pshare[tid] = p;
    }
    __syncthreads();

    if (tid < 16) {
        const int i = tid >> 2, j = tid & 3;
        const float denom = fmaxf(pshare[20], 1.0f);
        costl[tid] = -(pshare[i * 4 + j] + pshare[16 + i]) / denom;
    }
    __syncthreads();

    if (tid < 64) {
        constexpr int PERMS[24][4] = {
            {0,1,2,3},{0,1,3,2},{0,2,1,3},{0,2,3,1},{0,3,1,2},{0,3,2,1},
            {1,0,2,3},{1,0,3,2},{1,2,0,3},{1,2,3,0},{1,3,0,2},{1,3,2,0},
            {2,0,1,3},{2,0,3,1},{2,1,0,3},{2,1,3,0},{2,3,0,1},{2,3,1,0},
            {3,0,1,2},{3,0,2,1},{3,1,0,2},{3,1,2,0},{3,2,0,1},{3,2,1,0}};
        float s4 = 3.4e38f;
        if (tid < 24)
            s4 = costl[0 * 4 + PERMS[tid][0]] + costl[1 * 4 + PERMS[tid][1]]
               + costl[2 * 4 + PERMS[tid][2]] + costl[3 * 4 + PERMS[tid][3]];
        #pragma unroll
        for (int off = 32; off > 0; off >>= 1)
            s4 = fminf(s4, __shfl_xor(s4, off));
        if (tid == 0)   // per-batch loss, device-coherent store (no L2 flush)
            __hip_atomic_store(&ws[b], s4 * 0.25f,
                               __ATOMIC_RELAXED, __HIP_MEMORY_SCOPE_AGENT);
    }

    // __syncthreads drains vmcnt(0) -> ws[b] is at the coherent point
    // before tid 0 increments the ticket.
    __syncthreads();
    if (tid == 0)
        amLast = (__hip_atomic_fetch_add(ticket, 1u, __ATOMIC_RELAXED,
                                         __HIP_MEMORY_SCOPE_AGENT)
                  == BATCH - 1u);
    __syncthreads();
    if (!amLast) return;

    // ---- last-arriving block: mean of the 64 per-batch losses ----
    if (tid < 64) {
        float v = __hip_atomic_load(&ws[tid], __ATOMIC_RELAXED,
                                    __HIP_MEMORY_SCOPE_AGENT);
        #pragma unroll
        for (int off = 32; off > 0; off >>= 1)
            v += __shfl_xor(v, off);
        if (tid == 0) out[0] = v * (1.0f / BATCH);
    }
}

extern "C" void kernel_launch(void* const* d_in, const int* in_sizes, int n_in,
                              void* d_out, int out_size, void* d_ws, size_t ws_size,
                              hipStream_t stream) {
    const float* logits  = (const float*)d_in[0];
    const float* targets = (const float*)d_in[1];
    const float* mask    = (const float*)d_in[2];
    float* out = (float*)d_out;
    float* ws  = (float*)d_ws;
    unsigned int* ticket = (unsigned int*)(ws + TICKET_OFF);

    // zero the ticket each call (handles 0xAA poison + replay reset)
    hipMemsetAsync(ticket, 0, sizeof(unsigned int), stream);

    pit_batch<<<dim3(BATCH), NTHREADS, 0, stream>>>(
        logits, targets, mask, ws, ticket, out);
}

// Round 8
// 12.828 us; speedup vs baseline: 1.8441x; 1.6566x over previous
//
#include <hip/hip_runtime.h>
#include <math.h>

#define BATCH 64
#define TLEN 8000
#define NCHUNK 16
#define TPC (TLEN / NCHUNK)     // 500 frames per chunk
#define NPART 21                // 16 (M) + 4 (V) + 1 (mask sum)
#define NGROUP 4                // kernel2: chunks per thread-group
#define CPG (NCHUNK / NGROUP)   // 4 chunks per group

// fast, stable log-sigmoid: min(x,0) - log(1 + exp(-|x|))
__device__ __forceinline__ float log_sigmoid_f(float x) {
    float e = __expf(-fabsf(x));
    return fminf(x, 0.0f) - __logf(1.0f + e);
}

__global__ __launch_bounds__(256) void pit_partial(
    const float* __restrict__ logits, const float* __restrict__ targets,
    const float* __restrict__ mask, float* __restrict__ ws)
{
    const int chunk = blockIdx.x;   // 0..NCHUNK-1
    const int b     = blockIdx.y;   // 0..BATCH-1
    const int tid   = threadIdx.x;
    const int t0    = chunk * TPC;

    float M[4][4] = {{0.f}};
    float V[4] = {0.f};
    float msum = 0.f;

    const float4* lg4 = (const float4*)(logits  + (size_t)b * TLEN * 4);
    const float4* tg4 = (const float4*)(targets + (size_t)b * TLEN * 4);
    const float*  mk  = mask + (size_t)b * TLEN;

    for (int t = t0 + tid; t < t0 + TPC; t += 256) {
        float4 xv = lg4[t];
        float4 tv = tg4[t];
        float  m  = mk[t];
        float xs[4] = {xv.x, xv.y, xv.z, xv.w};
        float ts[4] = {tv.x, tv.y, tv.z, tv.w};
        msum += m;
        #pragma unroll
        for (int i = 0; i < 4; ++i) {
            float A  = log_sigmoid_f(xs[i]);
            float Bn = A - xs[i];            // log_sigmoid(-x)
            float C  = fmaf(0.5f, A, xs[i]); // POS_W*A - Bn with POS_W=1.5
            V[i] = fmaf(m, Bn, V[i]);
            float mc = m * C;
            #pragma unroll
            for (int j = 0; j < 4; ++j)
                M[i][j] = fmaf(mc, ts[j], M[i][j]);
        }
    }

    // ---- 3-stage deterministic LDS reduction (2 syncthreads) ----
    __shared__ float red[256 * NPART];          // 21504 B
    __shared__ float red2[8 * NPART];
    #pragma unroll
    for (int i = 0; i < 4; ++i)
        #pragma unroll
        for (int j = 0; j < 4; ++j)
            red[tid * NPART + i * 4 + j] = M[i][j];
    #pragma unroll
    for (int i = 0; i < 4; ++i) red[tid * NPART + 16 + i] = V[i];
    red[tid * NPART + 20] = msum;
    __syncthreads();

    {   // 8 segments x 21 parts = 168 workers, each sums 32 rows
        const int seg = tid >> 5;
        const int k   = tid & 31;
        if (k < NPART) {
            float acc = 0.f;
            #pragma unroll
            for (int i = 0; i < 32; ++i)
                acc += red[(seg * 32 + i) * NPART + k];
            red2[seg * NPART + k] = acc;
        }
    }
    __syncthreads();

    if (tid < NPART) {
        float acc = 0.f;
        #pragma unroll
        for (int s = 0; s < 8; ++s)
            acc += red2[s * NPART + tid];
        // ws layout: [chunk][part][batch] -> coalesced reads in pit_final
        ws[(chunk * NPART + tid) * BATCH + b] = acc;
    }
}

__global__ __launch_bounds__(256) void pit_final(
    const float* __restrict__ ws, float* __restrict__ out)
{
    const int tid = threadIdx.x;
    const int g   = tid >> 6;    // chunk group 0..3
    const int b   = tid & 63;    // batch element

    __shared__ float sh[NGROUP][BATCH][NPART];   // 21504 B

    // ---- stage A: 256 threads, each sums CPG chunks for (g, b) ----
    {
        float p[NPART];
        #pragma unroll
        for (int k = 0; k < NPART; ++k) p[k] = 0.f;
        #pragma unroll
        for (int c = 0; c < CPG; ++c)
            #pragma unroll
            for (int k = 0; k < NPART; ++k)
                p[k] += ws[((g * CPG + c) * NPART + k) * BATCH + b];
        #pragma unroll
        for (int k = 0; k < NPART; ++k) sh[g][b][k] = p[k];
    }
    __syncthreads();

    // ---- stage B: wave 0, one lane per batch ----
    if (tid < 64) {
        float p[NPART];
        #pragma unroll
        for (int k = 0; k < NPART; ++k) {
            float acc = sh[0][b][k];
            #pragma unroll
            for (int gg = 1; gg < NGROUP; ++gg) acc += sh[gg][b][k];
            p[k] = acc;
        }

        const float denom = fmaxf(p[20], 1.0f);
        float cost[4][4];
        #pragma unroll
        for (int i = 0; i < 4; ++i)
            #pragma unroll
            for (int j = 0; j < 4; ++j)
                cost[i][j] = -(p[i * 4 + j] + p[16 + i]) / denom;

        constexpr int PERMS[24][4] = {
            {0,1,2,3},{0,1,3,2},{0,2,1,3},{0,2,3,1},{0,3,1,2},{0,3,2,1},
            {1,0,2,3},{1,0,3,2},{1,2,0,3},{1,2,3,0},{1,3,0,2},{1,3,2,0},
            {2,0,1,3},{2,0,3,1},{2,1,0,3},{2,1,3,0},{2,3,0,1},{2,3,1,0},
            {3,0,1,2},{3,0,2,1},{3,1,0,2},{3,1,2,0},{3,2,0,1},{3,2,1,0}};
        float best = 3.4e38f;
        #pragma unroll
        for (int pi = 0; pi < 24; ++pi) {
            float s4 = cost[0][PERMS[pi][0]] + cost[1][PERMS[pi][1]]
                     + cost[2][PERMS[pi][2]] + cost[3][PERMS[pi][3]];
            best = fminf(best, s4);
        }
        float loss = best * 0.25f;

        // fixed-order 64-lane butterfly sum, then mean
        #pragma unroll
        for (int off = 32; off > 0; off >>= 1)
            loss += __shfl_xor(loss, off);
        if (tid == 0) out[0] = loss * (1.0f / BATCH);
    }
}

extern "C" void kernel_launch(void* const* d_in, const int* in_sizes, int n_in,
                              void* d_out, int out_size, void* d_ws, size_t ws_size,
                              hipStream_t stream) {
    const float* logits  = (const float*)d_in[0];
    const float* targets = (const float*)d_in[1];
    const float* mask    = (const float*)d_in[2];
    float* out = (float*)d_out;
    float* ws  = (float*)d_ws;

    pit_partial<<<dim3(NCHUNK, BATCH), 256, 0, stream>>>(logits, targets, mask, ws);
    pit_final<<<1, 256, 0, stream>>>(ws, out);
}